// Round 15
// baseline (77.124 us; speedup 1.0000x reference)
//
#include <hip/hip_runtime.h>
#include <hip/hip_bf16.h>
#include <math.h>

// Shapes: B=32, C=128, O=128, K=3, L=4096, W=1, PAD=1, DIL=1
// out[b,o,i] = sum_kc Wr[kc,o] * G[b,kc,i],  kc = k*128+c (K=384)
// G[b,kc,i] = wae[b,k,i]*x[b,c,addr] + wbe[b,k,i]*x[b,c,addr+1]
//
// r15 = r14 + LDS-cycle cuts (LDS pipe is ~80% busy per cycle model):
//   - packed bf16-pair window: win32[i] = bf16(x[i]) | bf16(x[i+1])<<16
//     -> interp = ONE ds_read_b32 (was ds_read2_b32 double-access)
//   - consumer tiling 2m x 4f (r11) with SINGLE Bl (r12) -> Bl reads halved
//     at unchanged 45 KB LDS / 3 blocks/CU.
//
// ws layout (bytes):
//   WrA @ 0       : bf16 A-frags, 8 m x 12 s x 64 lanes x 16B = 98304
//   wT  @ 98304   : float[128*32] transposed conv weights, wT[c*32+ch*3+tap]
//   addr2 @ 131072: int[32*3*4096]
//   wae @ 1703936 : float[32*3*4096]
//   wbe @ 3276800 : float[32*3*4096]

typedef __attribute__((ext_vector_type(8))) short bf16x8;
typedef __attribute__((ext_vector_type(4))) float f32x4;
typedef float f32x2u __attribute__((ext_vector_type(2), aligned(4)));

#define WIN 160
#define WP32 162   // u32 row stride: even (b64-aligned), bank shift 2/row

static __device__ inline unsigned short f2bf(float f) {
    __hip_bfloat16 h = __float2bfloat16(f);
    union { __hip_bfloat16 b; unsigned short u; } cv;
    cv.b = h;
    return cv.u;
}
static __device__ inline unsigned pk2(float a, float b) {
    return (unsigned)f2bf(a) | ((unsigned)f2bf(b) << 16);
}

// ---------- kernel 0: pack WrA (A-frags) + wT (transposed conv weights) ----------
// A-frag (m,s), lane l, elem e:  A[o = m*16+(l&15)][kc = s*32+(l>>4)*8+e]
__global__ __launch_bounds__(256) void k_wra(const float* __restrict__ w_reg,
                                             const float* __restrict__ w_off,
                                             const float* __restrict__ w_mod,
                                             unsigned short* __restrict__ WrA,
                                             float* __restrict__ wT) {
    int t = blockIdx.x * 256 + threadIdx.x;
    if (t < 8 * 12 * 64 * 8) {
        int e  = t & 7;
        int l  = (t >> 3) & 63;
        int ms = t >> 9;              // m*12 + s
        int m  = ms / 12;
        int s  = ms - m * 12;
        int o  = m * 16 + (l & 15);
        int kc = s * 32 + ((l >> 4) & 3) * 8 + e;
        int tap = kc >> 7;
        int c   = kc & 127;
        WrA[t] = f2bf(w_reg[(o * 128 + c) * 3 + tap]);
    } else if (t < 8 * 12 * 64 * 8 + 128 * 27) {
        int u = t - 8 * 12 * 64 * 8;
        int c = u / 27, r = u - c * 27;
        int ch = r / 3, tap = r - ch * 3;
        wT[c * 32 + r] = (ch < 6) ? w_off[(ch * 128 + c) * 3 + tap]
                                  : w_mod[((ch - 6) * 128 + c) * 3 + tap];
    }
}

// ---------- kernel 1: offset/mask conv, 8 waves x 16 channels (r9 exact) ----------
__global__ __launch_bounds__(512) void k_prep(const float* __restrict__ x,
                                              const float* __restrict__ wT,
                                              const float* __restrict__ b_off,
                                              const float* __restrict__ b_mod,
                                              int* __restrict__ addr2,
                                              float* __restrict__ wae,
                                              float* __restrict__ wbe) {
    __shared__ float red[7 * 64 * 19];            // 34 KB, stride 19 (odd)
    int t = threadIdx.x;
    int lane = t & 63;
    int wv = t >> 6;                              // 0..7
    int b = blockIdx.y;
    int i = blockIdx.x * 128 + lane * 2;          // lane covers i, i+1

    int c0 = __builtin_amdgcn_readfirstlane(wv) * 16;

    float acc[18];
#pragma unroll
    for (int z = 0; z < 18; ++z) acc[z] = 0.f;

    const float* xr = x + (size_t)b * 524288 + (size_t)c0 * 4096;
    const float* wbase = wT + c0 * 32;
#pragma unroll 2
    for (int c = 0; c < 16; ++c) {
        const float* row = xr + (size_t)c * 4096;
        f32x2u v = *(const f32x2u*)(row + i);
        float lm = row[max(i - 1, 0)];
        float rp = row[min(i + 2, 4095)];
        float left  = (i > 0)        ? lm : 0.f;
        float right = (i + 2 < 4096) ? rp : 0.f;
        const float* wrow = wbase + c * 32;       // wave-uniform -> s_load
#pragma unroll
        for (int ch = 0; ch < 9; ++ch) {
            float w0 = wrow[ch * 3 + 0];
            float w1 = wrow[ch * 3 + 1];
            float w2 = wrow[ch * 3 + 2];
            acc[ch * 2 + 0] += left * w0 + v.x * w1 + v.y  * w2;
            acc[ch * 2 + 1] += v.x  * w0 + v.y * w1 + right * w2;
        }
    }

    if (wv > 0) {
        float* r = &red[((wv - 1) * 64 + lane) * 19];
#pragma unroll
        for (int z = 0; z < 18; ++z) r[z] = acc[z];
    }
    __syncthreads();
    if (wv != 0) return;

#pragma unroll
    for (int p = 0; p < 7; ++p) {
        const float* r = &red[(p * 64 + lane) * 19];
#pragma unroll
        for (int z = 0; z < 18; ++z) acc[z] += r[z];
    }

#pragma unroll
    for (int k = 0; k < 3; ++k) {
        int   av[2];
        float wav[2], wbv[2];
#pragma unroll
        for (int ii = 0; ii < 2; ++ii) {
            float offy = acc[(2 * k) * 2 + ii]     + b_off[2 * k];
            float offx = acc[(2 * k + 1) * 2 + ii] + b_off[2 * k + 1];
            offy = fminf(fmaxf(offy, -1024.f), 1024.f);
            offx = fminf(fmaxf(offx, -1024.f), 1024.f);
            float am = acc[(6 + k) * 2 + ii] + b_mod[k];
            float m  = 2.f / (1.f + expf(-am));

            float py = (float)(i + ii - 1 + k) + offy;
            float y0 = floorf(py);
            int   iy0 = (int)y0;
            float wy1 = py - y0, wy0 = 1.f - wy1;
            float x0f = floorf(offx);
            int   ix0 = (int)x0f;
            float wx1 = offx - x0f, wx0 = 1.f - wx1;

            float sx = (ix0 == 0) ? wx0 : ((ix0 == -1) ? wx1 : 0.f);
            float scal = m * sx;

            float wAv = (iy0 >= 0 && iy0 < 4096)  ? scal * wy0 : 0.f;
            float wBv = (iy0 >= -1 && iy0 < 4095) ? scal * wy1 : 0.f;

            int addr = min(max(iy0, 0), 4094);
            bool eq = (iy0 == addr);
            wav[ii] = eq ? wAv : (iy0 == -1   ? wBv : 0.f);
            wbv[ii] = eq ? wBv : (iy0 == 4095 ? wAv : 0.f);
            av[ii] = addr;
        }
        int j = (b * 3 + k) * 4096 + i;
        *(int2*)(addr2 + j)  = make_int2(av[0], av[1]);
        *(f32x2u*)(wae + j)  = (f32x2u){wav[0], wav[1]};
        *(f32x2u*)(wbe + j)  = (f32x2u){wbv[0], wbv[1]};
    }
}

// ---------- kernel 2: fused gather + MFMA GEMM ----------
// grid (32 i-tiles, 32 b), 512 threads = 8 waves. Block: 128 i x 128 o.
// Producer: wave w interps i-frag w -> Bl[w][k] (single buffer).
// Consumer: wave w = m-group (w&3: 2 m-frags) x i-half (w>>2: 4 i-frags).
// Window = packed bf16 pairs; raw lgkm-only barriers (r14).
__global__ __launch_bounds__(512) void k_fused(const unsigned short* __restrict__ WrA,
                                               const float* __restrict__ x,
                                               const int* __restrict__ addr2,
                                               const float* __restrict__ wae,
                                               const float* __restrict__ wbe,
                                               float* __restrict__ out) {
    __shared__ unsigned win32[32 * WP32];          // 20.7 KB packed pairs
    __shared__ short Bl[8][3][512];                // 24 KB single buffer
    int t = threadIdx.x;
    int l = t & 63;
    int w = t >> 6;                                // 0..7
    int b  = blockIdx.y;
    int ib = blockIdx.x;
    int q = l >> 4;
    int il = l & 15;
    int mg = w & 3;                                // consumer m-group
    int hh = w >> 2;                               // consumer i-half
    int i0t = ib * 128;
    int i0p = i0t + w * 16 + il;                   // producer's i
    int wsod = i0t - 16;
    if (wsod > 4096 - WIN) wsod = 4096 - WIN;
    if (wsod < 0) wsod = 0;
    const float* xb = x + (size_t)b * 524288;
    const bf16x8* Ag = (const bf16x8*)WrA;

    // staging geometry: chunk idx = it*512+t covers row r, cols 4cp..4cp+3
    int  rr_[3], cp_[3];
    bool v_[3];
#pragma unroll
    for (int it = 0; it < 3; ++it) {
        int idx = it * 512 + t;
        int r = idx / 40;
        rr_[it] = r;
        cp_[it] = idx - r * 40;
        v_[it]  = (idx < 1280);
    }

    // producer gather params + wave-uniform in-window flags
    int   a_[3];
    float wa_[3], wb_[3];
    bool  okw[3];
#pragma unroll
    for (int k = 0; k < 3; ++k) {
        int j = (b * 3 + k) * 4096 + i0p;
        int a = addr2[j];
        a_[k]  = a;
        wa_[k] = wae[j];
        wb_[k] = wbe[j];
        okw[k] = (bool)__all(a >= wsod && a <= wsod + WIN - 2);
    }

    f32x4 acc[2][4];
#pragma unroll
    for (int mm = 0; mm < 2; ++mm)
#pragma unroll
        for (int ff = 0; ff < 4; ++ff) acc[mm][ff] = (f32x4){0.f, 0.f, 0.f, 0.f};

    // prologue: stage window for cc=0 (pack to bf16 pairs)
#pragma unroll
    for (int it = 0; it < 3; ++it) {
        if (v_[it]) {
            const float* row = xb + (size_t)rr_[it] * 4096;
            int c0 = wsod + cp_[it] * 4;
            float4 v = *(const float4*)(row + c0);
            float nx = row[min(c0 + 4, 4095)];
            unsigned* d = &win32[rr_[it] * WP32 + cp_[it] * 4];
            *(uint2*)(d)     = make_uint2(pk2(v.x, v.y), pk2(v.y, v.z));
            *(uint2*)(d + 2) = make_uint2(pk2(v.z, v.w), pk2(v.w, nx));
        }
    }
    __syncthreads();

    for (int cc = 0; cc < 4; ++cc) {
        int cb = cc * 32;

        // consumer A-frags first (oldest VMEM; stg loads queue behind)
        bf16x8 Areg[2][3];
#pragma unroll
        for (int mm = 0; mm < 2; ++mm)
#pragma unroll
            for (int k = 0; k < 3; ++k)
                Areg[mm][k] = Ag[((mg * 2 + mm) * 12 + k * 4 + cc) * 64 + l];

        // --- producer: interp own i-frag -> B LDS (1 ds_read_b32 per elem) ---
#pragma unroll
        for (int k = 0; k < 3; ++k) {
            float v[8];
            float wa = wa_[k], wb = wb_[k];
            if (okw[k]) {
                int pos = a_[k] - wsod;
#pragma unroll
                for (int e = 0; e < 8; ++e) {
                    unsigned u = win32[(q * 8 + e) * WP32 + pos];
                    float lo = __uint_as_float(u << 16);
                    float hi = __uint_as_float(u & 0xffff0000u);
                    v[e] = wa * lo + wb * hi;
                }
            } else {
                int a = a_[k];
#pragma unroll
                for (int e = 0; e < 8; ++e) {
                    const float* row = xb + (size_t)(cb + q * 8 + e) * 4096;
                    f32x2u p2 = *(const f32x2u*)(row + a);
                    v[e] = wa * p2.x + wb * p2.y;
                }
            }
            bf16x8 Bv;
#pragma unroll
            for (int e = 0; e < 8; ++e) Bv[e] = (short)f2bf(v[e]);
            *(bf16x8*)&Bl[w][k][l * 8] = Bv;
        }

        // --- issue next window's loads; stay in flight across barrier #1 ---
        float4 sv[3];
        float  sn[3];
        if (cc < 3) {
#pragma unroll
            for (int it = 0; it < 3; ++it) {
                if (v_[it]) {
                    const float* row = xb + (size_t)(cb + 32 + rr_[it]) * 4096;
                    int c0 = wsod + cp_[it] * 4;
                    sv[it] = *(const float4*)(row + c0);
                    sn[it] = row[min(c0 + 4, 4095)];
                }
            }
        }

        // barrier #1: Bl writes + win reads complete (LDS only, no vmcnt drain)
        asm volatile("s_waitcnt lgkmcnt(0)" ::: "memory");
        __builtin_amdgcn_sched_barrier(0);
        __builtin_amdgcn_s_barrier();

        // --- consumer: pure LDS + MFMA (stg HBM latency hides under this) ---
        __builtin_amdgcn_s_setprio(1);
#pragma unroll
        for (int ff = 0; ff < 4; ++ff) {
            int f = hh * 4 + ff;
#pragma unroll
            for (int k = 0; k < 3; ++k) {
                bf16x8 Bv = *(const bf16x8*)&Bl[f][k][l * 8];
                acc[0][ff] = __builtin_amdgcn_mfma_f32_16x16x32_bf16(Areg[0][k], Bv, acc[0][ff], 0, 0, 0);
                acc[1][ff] = __builtin_amdgcn_mfma_f32_16x16x32_bf16(Areg[1][k], Bv, acc[1][ff], 0, 0, 0);
            }
        }
        __builtin_amdgcn_s_setprio(0);

        // --- pack + write staged window (vmcnt drains here, post-MFMA) ---
        if (cc < 3) {
#pragma unroll
            for (int it = 0; it < 3; ++it) {
                if (v_[it]) {
                    unsigned* d = &win32[rr_[it] * WP32 + cp_[it] * 4];
                    *(uint2*)(d)     = make_uint2(pk2(sv[it].x, sv[it].y), pk2(sv[it].y, sv[it].z));
                    *(uint2*)(d + 2) = make_uint2(pk2(sv[it].z, sv[it].w), pk2(sv[it].w, sn[it]));
                }
            }
            // barrier #2: win writes visible + all Bl reads done (LDS only)
            asm volatile("s_waitcnt lgkmcnt(0)" ::: "memory");
            __builtin_amdgcn_sched_barrier(0);
            __builtin_amdgcn_s_barrier();
        }
    }

    // C layout: col = lane&15, row = (lane>>4)*4 + reg.
    // Consumer wave w -> o rows mg*32..+32, i cols i0t + hh*64..+64.
    int r0 = q * 4;
#pragma unroll
    for (int mm = 0; mm < 2; ++mm) {
#pragma unroll
        for (int ff = 0; ff < 4; ++ff) {
#pragma unroll
            for (int r = 0; r < 4; ++r) {
                int o = (mg * 2 + mm) * 16 + r0 + r;
                out[((size_t)(b * 128 + o)) * 4096 + i0t + (hh * 4 + ff) * 16 + il] = acc[mm][ff][r];
            }
        }
    }
}

extern "C" void kernel_launch(void* const* d_in, const int* in_sizes, int n_in,
                              void* d_out, int out_size, void* d_ws, size_t ws_size,
                              hipStream_t stream) {
    const float* x     = (const float*)d_in[0];
    const float* w_off = (const float*)d_in[1];
    const float* b_off = (const float*)d_in[2];
    const float* w_mod = (const float*)d_in[3];
    const float* b_mod = (const float*)d_in[4];
    const float* w_reg = (const float*)d_in[5];
    float* out = (float*)d_out;

    char* ws = (char*)d_ws;
    unsigned short* WrA = (unsigned short*)(ws);
    float* wT    = (float*)(ws + 98304);
    int*   addr2 = (int*)  (ws + 131072);
    float* wae   = (float*)(ws + 1703936);
    float* wbe   = (float*)(ws + 3276800);

    k_wra<<<206, 256, 0, stream>>>(w_reg, w_off, w_mod, WrA, wT);
    k_prep<<<dim3(32, 32), 512, 0, stream>>>(x, wT, b_off, b_mod,
                                             addr2, wae, wbe);
    k_fused<<<dim3(32, 32), 512, 0, stream>>>(WrA, x, addr2, wae, wbe, out);
}

// Round 16
// 67.418 us; speedup vs baseline: 1.1440x; 1.1440x over previous
//
#include <hip/hip_runtime.h>
#include <hip/hip_bf16.h>
#include <math.h>

// Shapes: B=32, C=128, O=128, K=3, L=4096, W=1, PAD=1, DIL=1
// out[b,o,i] = sum_kc Wr[kc,o] * G[b,kc,i],  kc = k*128+c (K=384)
// G[b,kc,i] = wae[b,k,i]*x[b,c,addr] + wbe[b,k,i]*x[b,c,addr+1]
//
// r16 = r12 consumer (VGPR-64 config: wave w = m-frag w, Areg[3], acc[8])
//     + r15 packed-bf16 window (conflicts 4.59M -> 0.88M, validated)
//     + pack-early staging (uint4 sp[3] = same 12 live regs as r12's stg[3];
//       vmcnt drains at the pack -- r14 proved drain placement neutral).
//
// ws layout (bytes):
//   WrA @ 0       : bf16 A-frags, 8 m x 12 s x 64 lanes x 16B = 98304
//   wT  @ 98304   : float[128*32] transposed conv weights, wT[c*32+ch*3+tap]
//   addr2 @ 131072: int[32*3*4096]
//   wae @ 1703936 : float[32*3*4096]
//   wbe @ 3276800 : float[32*3*4096]

typedef __attribute__((ext_vector_type(8))) short bf16x8;
typedef __attribute__((ext_vector_type(4))) float f32x4;
typedef float f32x2u __attribute__((ext_vector_type(2), aligned(4)));

#define WIN 160
#define WP32 162   // u32 row stride: even (b64-aligned), bank shift 2/row

static __device__ inline unsigned short f2bf(float f) {
    __hip_bfloat16 h = __float2bfloat16(f);
    union { __hip_bfloat16 b; unsigned short u; } cv;
    cv.b = h;
    return cv.u;
}
static __device__ inline unsigned pk2(float a, float b) {
    return (unsigned)f2bf(a) | ((unsigned)f2bf(b) << 16);
}

// ---------- kernel 0: pack WrA (A-frags) + wT (transposed conv weights) ----------
// A-frag (m,s), lane l, elem e:  A[o = m*16+(l&15)][kc = s*32+(l>>4)*8+e]
__global__ __launch_bounds__(256) void k_wra(const float* __restrict__ w_reg,
                                             const float* __restrict__ w_off,
                                             const float* __restrict__ w_mod,
                                             unsigned short* __restrict__ WrA,
                                             float* __restrict__ wT) {
    int t = blockIdx.x * 256 + threadIdx.x;
    if (t < 8 * 12 * 64 * 8) {
        int e  = t & 7;
        int l  = (t >> 3) & 63;
        int ms = t >> 9;              // m*12 + s
        int m  = ms / 12;
        int s  = ms - m * 12;
        int o  = m * 16 + (l & 15);
        int kc = s * 32 + ((l >> 4) & 3) * 8 + e;
        int tap = kc >> 7;
        int c   = kc & 127;
        WrA[t] = f2bf(w_reg[(o * 128 + c) * 3 + tap]);
    } else if (t < 8 * 12 * 64 * 8 + 128 * 27) {
        int u = t - 8 * 12 * 64 * 8;
        int c = u / 27, r = u - c * 27;
        int ch = r / 3, tap = r - ch * 3;
        wT[c * 32 + r] = (ch < 6) ? w_off[(ch * 128 + c) * 3 + tap]
                                  : w_mod[((ch - 6) * 128 + c) * 3 + tap];
    }
}

// ---------- kernel 1: offset/mask conv, 8 waves x 16 channels (r9 exact) ----------
__global__ __launch_bounds__(512) void k_prep(const float* __restrict__ x,
                                              const float* __restrict__ wT,
                                              const float* __restrict__ b_off,
                                              const float* __restrict__ b_mod,
                                              int* __restrict__ addr2,
                                              float* __restrict__ wae,
                                              float* __restrict__ wbe) {
    __shared__ float red[7 * 64 * 19];            // 34 KB, stride 19 (odd)
    int t = threadIdx.x;
    int lane = t & 63;
    int wv = t >> 6;                              // 0..7
    int b = blockIdx.y;
    int i = blockIdx.x * 128 + lane * 2;          // lane covers i, i+1

    int c0 = __builtin_amdgcn_readfirstlane(wv) * 16;

    float acc[18];
#pragma unroll
    for (int z = 0; z < 18; ++z) acc[z] = 0.f;

    const float* xr = x + (size_t)b * 524288 + (size_t)c0 * 4096;
    const float* wbase = wT + c0 * 32;
#pragma unroll 2
    for (int c = 0; c < 16; ++c) {
        const float* row = xr + (size_t)c * 4096;
        f32x2u v = *(const f32x2u*)(row + i);
        float lm = row[max(i - 1, 0)];
        float rp = row[min(i + 2, 4095)];
        float left  = (i > 0)        ? lm : 0.f;
        float right = (i + 2 < 4096) ? rp : 0.f;
        const float* wrow = wbase + c * 32;       // wave-uniform -> s_load
#pragma unroll
        for (int ch = 0; ch < 9; ++ch) {
            float w0 = wrow[ch * 3 + 0];
            float w1 = wrow[ch * 3 + 1];
            float w2 = wrow[ch * 3 + 2];
            acc[ch * 2 + 0] += left * w0 + v.x * w1 + v.y  * w2;
            acc[ch * 2 + 1] += v.x  * w0 + v.y * w1 + right * w2;
        }
    }

    if (wv > 0) {
        float* r = &red[((wv - 1) * 64 + lane) * 19];
#pragma unroll
        for (int z = 0; z < 18; ++z) r[z] = acc[z];
    }
    __syncthreads();
    if (wv != 0) return;

#pragma unroll
    for (int p = 0; p < 7; ++p) {
        const float* r = &red[(p * 64 + lane) * 19];
#pragma unroll
        for (int z = 0; z < 18; ++z) acc[z] += r[z];
    }

#pragma unroll
    for (int k = 0; k < 3; ++k) {
        int   av[2];
        float wav[2], wbv[2];
#pragma unroll
        for (int ii = 0; ii < 2; ++ii) {
            float offy = acc[(2 * k) * 2 + ii]     + b_off[2 * k];
            float offx = acc[(2 * k + 1) * 2 + ii] + b_off[2 * k + 1];
            offy = fminf(fmaxf(offy, -1024.f), 1024.f);
            offx = fminf(fmaxf(offx, -1024.f), 1024.f);
            float am = acc[(6 + k) * 2 + ii] + b_mod[k];
            float m  = 2.f / (1.f + expf(-am));

            float py = (float)(i + ii - 1 + k) + offy;
            float y0 = floorf(py);
            int   iy0 = (int)y0;
            float wy1 = py - y0, wy0 = 1.f - wy1;
            float x0f = floorf(offx);
            int   ix0 = (int)x0f;
            float wx1 = offx - x0f, wx0 = 1.f - wx1;

            float sx = (ix0 == 0) ? wx0 : ((ix0 == -1) ? wx1 : 0.f);
            float scal = m * sx;

            float wAv = (iy0 >= 0 && iy0 < 4096)  ? scal * wy0 : 0.f;
            float wBv = (iy0 >= -1 && iy0 < 4095) ? scal * wy1 : 0.f;

            int addr = min(max(iy0, 0), 4094);
            bool eq = (iy0 == addr);
            wav[ii] = eq ? wAv : (iy0 == -1   ? wBv : 0.f);
            wbv[ii] = eq ? wBv : (iy0 == 4095 ? wAv : 0.f);
            av[ii] = addr;
        }
        int j = (b * 3 + k) * 4096 + i;
        *(int2*)(addr2 + j)  = make_int2(av[0], av[1]);
        *(f32x2u*)(wae + j)  = (f32x2u){wav[0], wav[1]};
        *(f32x2u*)(wbe + j)  = (f32x2u){wbv[0], wbv[1]};
    }
}

// ---------- kernel 2: fused gather + MFMA GEMM ----------
// grid (32 i-tiles, 32 b), 512 threads = 8 waves. Block: 128 i x 128 o.
// Producer: wave w interps i-frag w -> Bl[w][k] (single buffer, packed window).
// Consumer: wave w = m-frag w (r12 VGPR-64 config), A-frags in registers.
__global__ __launch_bounds__(512) void k_fused(const unsigned short* __restrict__ WrA,
                                               const float* __restrict__ x,
                                               const int* __restrict__ addr2,
                                               const float* __restrict__ wae,
                                               const float* __restrict__ wbe,
                                               float* __restrict__ out) {
    __shared__ unsigned win32[32 * WP32];          // 20.7 KB packed bf16 pairs
    __shared__ short Bl[8][3][512];                // 24 KB single buffer
    int t = threadIdx.x;
    int l = t & 63;
    int w = t >> 6;                                // 0..7
    int b  = blockIdx.y;
    int ib = blockIdx.x;
    int q = l >> 4;
    int il = l & 15;
    int i0t = ib * 128;
    int i0p = i0t + w * 16 + il;                   // producer's i
    int wsod = i0t - 16;
    if (wsod > 4096 - WIN) wsod = 4096 - WIN;
    if (wsod < 0) wsod = 0;
    const float* xb = x + (size_t)b * 524288;
    const bf16x8* Ag = (const bf16x8*)WrA;

    // producer gather params + wave-uniform in-window flags
    int   a_[3];
    float wa_[3], wb_[3];
    bool  okw[3];
#pragma unroll
    for (int k = 0; k < 3; ++k) {
        int j = (b * 3 + k) * 4096 + i0p;
        int a = addr2[j];
        a_[k]  = a;
        wa_[k] = wae[j];
        wb_[k] = wbe[j];
        okw[k] = (bool)__all(a >= wsod && a <= wsod + WIN - 2);
    }

    f32x4 acc[8];
#pragma unroll
    for (int f = 0; f < 8; ++f) acc[f] = (f32x4){0.f, 0.f, 0.f, 0.f};

    // prologue: load + pack + write window for cc=0
#pragma unroll
    for (int it = 0; it < 3; ++it) {
        int idx = it * 512 + t;
        if (idx < 1280) {
            int r = idx / 40, cp = idx - r * 40;
            const float* row = xb + (size_t)r * 4096;
            int c0 = wsod + cp * 4;
            float4 v = *(const float4*)(row + c0);
            float nx = row[min(c0 + 4, 4095)];
            unsigned* d = &win32[r * WP32 + cp * 4];
            *(uint2*)(d)     = make_uint2(pk2(v.x, v.y), pk2(v.y, v.z));
            *(uint2*)(d + 2) = make_uint2(pk2(v.z, v.w), pk2(v.w, nx));
        }
    }
    __syncthreads();

    for (int cc = 0; cc < 4; ++cc) {
        int cb = cc * 32;

        // consumer A-frags (3 loads/phase, r12 config)
        bf16x8 Areg[3];
#pragma unroll
        for (int k = 0; k < 3; ++k)
            Areg[k] = Ag[(w * 12 + k * 4 + cc) * 64 + l];

        // --- producer: interp own i-frag (1 ds_read_b32/elem) -> B LDS ---
#pragma unroll
        for (int k = 0; k < 3; ++k) {
            float v[8];
            float wa = wa_[k], wb = wb_[k];
            if (okw[k]) {
                int pos = a_[k] - wsod;
#pragma unroll
                for (int e = 0; e < 8; ++e) {
                    unsigned u = win32[(q * 8 + e) * WP32 + pos];
                    float lo = __uint_as_float(u << 16);
                    float hi = __uint_as_float(u & 0xffff0000u);
                    v[e] = wa * lo + wb * hi;
                }
            } else {
                int a = a_[k];
#pragma unroll
                for (int e = 0; e < 8; ++e) {
                    const float* row = xb + (size_t)(cb + q * 8 + e) * 4096;
                    f32x2u p2 = *(const f32x2u*)(row + a);
                    v[e] = wa * p2.x + wb * p2.y;
                }
            }
            bf16x8 Bv;
#pragma unroll
            for (int e = 0; e < 8; ++e) Bv[e] = (short)f2bf(v[e]);
            *(bf16x8*)&Bl[w][k][l * 8] = Bv;
        }

        // --- load + PACK next window early: only uint4 sp[3] (12 regs)
        //     stays live across the MFMA (same footprint as r12's stg[3]) ---
        uint4 sp[3];
        if (cc < 3) {
#pragma unroll
            for (int it = 0; it < 3; ++it) {
                int idx = it * 512 + t;
                if (idx < 1280) {
                    int r = idx / 40, cp = idx - r * 40;
                    const float* row = xb + (size_t)(cb + 32 + r) * 4096;
                    int c0 = wsod + cp * 4;
                    float4 v = *(const float4*)(row + c0);
                    float nx = row[min(c0 + 4, 4095)];
                    sp[it] = make_uint4(pk2(v.x, v.y), pk2(v.y, v.z),
                                        pk2(v.z, v.w), pk2(v.w, nx));
                }
            }
        }

        // barrier #1: Bl writes + win reads complete (LDS-only wait)
        asm volatile("s_waitcnt lgkmcnt(0)" ::: "memory");
        __builtin_amdgcn_sched_barrier(0);
        __builtin_amdgcn_s_barrier();

        // --- consumer: pure LDS + MFMA ---
        __builtin_amdgcn_s_setprio(1);
#pragma unroll
        for (int f = 0; f < 8; ++f) {
#pragma unroll
            for (int k = 0; k < 3; ++k) {
                bf16x8 Bv = *(const bf16x8*)&Bl[f][k][l * 8];
                acc[f] = __builtin_amdgcn_mfma_f32_16x16x32_bf16(Areg[k], Bv, acc[f], 0, 0, 0);
            }
        }
        __builtin_amdgcn_s_setprio(0);

        // --- write packed window; barrier #2 closes phase ---
        if (cc < 3) {
#pragma unroll
            for (int it = 0; it < 3; ++it) {
                int idx = it * 512 + t;
                if (idx < 1280) {
                    int r = idx / 40, cp = idx - r * 40;
                    unsigned* d = &win32[r * WP32 + cp * 4];
                    *(uint2*)(d)     = make_uint2(sp[it].x, sp[it].y);
                    *(uint2*)(d + 2) = make_uint2(sp[it].z, sp[it].w);
                }
            }
            asm volatile("s_waitcnt lgkmcnt(0)" ::: "memory");
            __builtin_amdgcn_sched_barrier(0);
            __builtin_amdgcn_s_barrier();
        }
    }

    // C layout: col = lane&15, row = (lane>>4)*4 + reg. Wave w -> o rows w*16..+15.
    int r0 = q * 4;
#pragma unroll
    for (int f = 0; f < 8; ++f) {
#pragma unroll
        for (int r = 0; r < 4; ++r) {
            int o = w * 16 + r0 + r;
            out[((size_t)(b * 128 + o)) * 4096 + i0t + f * 16 + il] = acc[f][r];
        }
    }
}

extern "C" void kernel_launch(void* const* d_in, const int* in_sizes, int n_in,
                              void* d_out, int out_size, void* d_ws, size_t ws_size,
                              hipStream_t stream) {
    const float* x     = (const float*)d_in[0];
    const float* w_off = (const float*)d_in[1];
    const float* b_off = (const float*)d_in[2];
    const float* w_mod = (const float*)d_in[3];
    const float* b_mod = (const float*)d_in[4];
    const float* w_reg = (const float*)d_in[5];
    float* out = (float*)d_out;

    char* ws = (char*)d_ws;
    unsigned short* WrA = (unsigned short*)(ws);
    float* wT    = (float*)(ws + 98304);
    int*   addr2 = (int*)  (ws + 131072);
    float* wae   = (float*)(ws + 1703936);
    float* wbe   = (float*)(ws + 3276800);

    k_wra<<<206, 256, 0, stream>>>(w_reg, w_off, w_mod, WrA, wT);
    k_prep<<<dim3(32, 32), 512, 0, stream>>>(x, wT, b_off, b_mod,
                                             addr2, wae, wbe);
    k_fused<<<dim3(32, 32), 512, 0, stream>>>(WrA, x, addr2, wae, wbe, out);
}